// Round 21
// baseline (35.817 us; speedup 1.0000x reference)
//
#include <hip/hip_runtime.h>

// BertWordEmbedder: B=64, T=512, H=768, W=256, D=256
// TWO kernels, no intermediate we:
//   prep_wt2: proj_w [768][256] f32 -> wt2 TILED bf16 [ct=16][kc=96][16col][8k]
//   fused:    R21 = R20 design (balanced phase A) with macro-capture fix:
//             A-tile zero-init; 32 words partitioned into 8 contiguous,
//             token-count-balanced word ranges (from sb[] prefix); each wave
//             streams its range as ONE token stream (4-token unroll, 12 loads
//             in flight), flushing at word boundaries into dynamic LDS rows.
//             Phase B: wave = 32x32 (2Mx2N), zero-barrier K-loop (unchanged).
// Empty words: zero A row (from init) -> out = bias (matches reference).
// ws: [0) wt2 393216 B

#define NB 64
#define NT 512
#define NH 768
#define NW 256
#define ND 256
#define PAD 8
#define ROWE (NH + PAD)   // 776

typedef __attribute__((ext_vector_type(8))) short short8;
typedef __attribute__((ext_vector_type(4))) float f32x4;
typedef __attribute__((ext_vector_type(4))) float float4v;
typedef __attribute__((ext_vector_type(4))) unsigned int uint4v;
typedef __attribute__((ext_vector_type(4))) unsigned short ushort4v;

__device__ __forceinline__ unsigned short f2bf(float f) {
    union { float f; unsigned u; } v; v.f = f;
    unsigned r = v.u + 0x7fffu + ((v.u >> 16) & 1u);  // RNE
    return (unsigned short)(r >> 16);
}

// proj_w -> tiled wt2 (CONTROL, R15-proven)
__global__ void prep_wt2(const float* __restrict__ w, unsigned short* __restrict__ wt2) {
    __shared__ float tile[32][33];
    const int tid = threadIdx.x, n = blockIdx.x;
    const int tx = tid & 31, ty = tid >> 5;
    const int k0 = (n % 24) * 32, n0 = (n / 24) * 32;
    #pragma unroll
    for (int i = 0; i < 4; ++i)
        tile[ty + 8 * i][tx] = w[(size_t)(k0 + ty + 8 * i) * ND + n0 + tx];
    __syncthreads();
    if (tid < 128) {
        const int cc = tid & 31, q = tid >> 5;
        const int col = n0 + cc;
        ushort4v u0, u1;
        #pragma unroll
        for (int j = 0; j < 4; ++j) u0[j] = f2bf(tile[q * 8 + j][cc]);
        #pragma unroll
        for (int j = 0; j < 4; ++j) u1[j] = f2bf(tile[q * 8 + 4 + j][cc]);
        size_t off = (((size_t)(col >> 4) * 96 + (k0 >> 3) + q) * 16 + (col & 15)) * 8;
        *(ushort4v*)&wt2[off]     = u0;
        *(ushort4v*)&wt2[off + 4] = u1;
    }
}

// fused pool+GEMM. 512 blocks = (b, 32-word group), 512 thr = 8 waves.
__global__ __launch_bounds__(512, 4)
void fused(const float* __restrict__ hs, const int* __restrict__ wid,
           const unsigned short* __restrict__ wt2, const float* __restrict__ pb,
           float* __restrict__ out) {
    __shared__ unsigned short A[32][ROWE];   // 49664 B
    __shared__ int swid[NT];
    __shared__ int sb[33];

    const int tid = threadIdx.x, bid = blockIdx.x;
    const int wave = tid >> 6, lane = tid & 63;
    const int b = bid >> 3, w0 = (bid & 7) * 32;

    // zero-init A data region (32 rows x 96 16B-chunks; 6 chunks/thread)
    {
        uint4v z = {0, 0, 0, 0};
        int c0 = tid * 6;
        #pragma unroll
        for (int i = 0; i < 6; ++i) {
            int c = c0 + i;
            int r = c / 96, k = (c % 96) * 8;
            *(uint4v*)&A[r][k] = z;
        }
    }
    swid[tid] = wid[b * NT + tid];
    __syncthreads();
    if (tid <= 32) {
        int v = w0 + tid, lo = 0, hi = NT;
        while (lo < hi) { int mid = (lo + hi) >> 1; if (swid[mid] < v) lo = mid + 1; else hi = mid; }
        sb[tid] = lo;
    }
    __syncthreads();

    // ---- Phase A: balanced token partition across the 8 waves ----
    const float* base = hs + (size_t)b * NT * NH + lane * 4;
    {
        const int t0a = sb[0], total = sb[32] - sb[0];
        int wa = 32, wb = 32;
        {
            const int tgA = t0a + (int)(((long)wave * total) >> 3);
            const int tgB = t0a + (int)(((long)(wave + 1) * total) >> 3);
            for (int i = 0; i <= 32; ++i) { if (sb[i] >= tgA) { wa = i; break; } }
            for (int i = 0; i <= 32; ++i) { if (sb[i] >= tgB) { wb = i; break; } }
        }
        const int tstart = sb[wa], tend = sb[wb];

        if (tstart < tend) {
            int wptr = wa;
            while (sb[wptr + 1] <= tstart) ++wptr;   // skip empty leading words
            int sEnd = sb[wptr + 1];
            int segStart = tstart;

            float4v ac0 = {0,0,0,0}, ac1 = {0,0,0,0}, ac2 = {0,0,0,0};

#define FLUSH(t_) {                                                           \
            const float sc_ = 1.0f / (float)(sEnd - segStart);                \
            ushort4v uu_;                                                     \
            _Pragma("unroll") for (int q_ = 0; q_ < 4; ++q_) uu_[q_] = f2bf(ac0[q_] * sc_); \
            *(ushort4v*)&A[wptr][lane * 4] = uu_;                             \
            _Pragma("unroll") for (int q_ = 0; q_ < 4; ++q_) uu_[q_] = f2bf(ac1[q_] * sc_); \
            *(ushort4v*)&A[wptr][256 + lane * 4] = uu_;                       \
            _Pragma("unroll") for (int q_ = 0; q_ < 4; ++q_) uu_[q_] = f2bf(ac2[q_] * sc_); \
            *(ushort4v*)&A[wptr][512 + lane * 4] = uu_;                       \
            ac0 = (float4v){0,0,0,0}; ac1 = (float4v){0,0,0,0}; ac2 = (float4v){0,0,0,0}; \
            if ((t_) + 1 < tend) {                                            \
                do { ++wptr; } while (sb[wptr + 1] <= (t_) + 1);              \
                segStart = (t_) + 1; sEnd = sb[wptr + 1];                     \
            }                                                                 \
        }
#define STEP(tt, v0, v1, v2) {                                                \
            const int tcur_ = (tt);                                           \
            _Pragma("unroll") for (int q_ = 0; q_ < 4; ++q_) {                \
                ac0[q_] += (v0)[q_]; ac1[q_] += (v1)[q_]; ac2[q_] += (v2)[q_]; } \
            if (tcur_ + 1 == sEnd) FLUSH(tcur_);                              \
        }

            int t = tstart;
            for (; t + 4 <= tend; t += 4) {          // 12 x 1KB loads in flight
                float4v v[4][3];
                #pragma unroll
                for (int u = 0; u < 4; ++u) {
                    const float* p2 = base + (size_t)(t + u) * NH;
                    v[u][0] = *(const float4v*)(p2);
                    v[u][1] = *(const float4v*)(p2 + 256);
                    v[u][2] = *(const float4v*)(p2 + 512);
                }
                #pragma unroll
                for (int u = 0; u < 4; ++u) STEP(t + u, v[u][0], v[u][1], v[u][2]);
            }
            for (; t < tend; ++t) {
                const float* p2 = base + (size_t)t * NH;
                float4v v0 = *(const float4v*)(p2);
                float4v v1 = *(const float4v*)(p2 + 256);
                float4v v2 = *(const float4v*)(p2 + 512);
                STEP(t, v0, v1, v2);
            }
#undef STEP
#undef FLUSH
        }
    }
    __syncthreads();

    // ---- Phase B: GEMM [32x768]x[768x256]; wave = 32x32 (2Mx2N)  [R18] ----
    const int cl = lane & 15, kg = lane >> 4;
    const int c0w = wave * 32;
    const unsigned short* bgp = wt2 + (size_t)(wave * 2) * 12288 + kg * 128 + cl * 8;

    short8 a0f[2], a1f[2], b0f[2], b1f[2];
    f32x4 acc[2][2];
    #pragma unroll
    for (int mt = 0; mt < 2; ++mt)
        #pragma unroll
        for (int nt = 0; nt < 2; ++nt)
            #pragma unroll
            for (int r = 0; r < 4; ++r) acc[mt][nt][r] = 0.f;

#define LDA(d, ks) { d[0] = *(const short8*)&A[cl][(ks) * 32 + kg * 8];       \
                     d[1] = *(const short8*)&A[16 + cl][(ks) * 32 + kg * 8]; }
#define LDB(d, ks) { _Pragma("unroll")                                        \
                     for (int nt = 0; nt < 2; ++nt)                           \
                         d[nt] = *(const short8*)(bgp + nt * 12288 + (ks) * 512); }
#define MM(a, bb) { _Pragma("unroll")                                         \
                    for (int mt = 0; mt < 2; ++mt)                            \
                        _Pragma("unroll")                                     \
                        for (int nt = 0; nt < 2; ++nt)                        \
                            acc[mt][nt] = __builtin_amdgcn_mfma_f32_16x16x32_bf16(a[mt], bb[nt], acc[mt][nt], 0, 0, 0); }

    LDA(a0f, 0); LDB(b0f, 0);
    #pragma unroll 1
    for (int i = 0; i < 12; ++i) {
        const int ks = 2 * i;
        LDA(a1f, ks + 1); LDB(b1f, ks + 1);
        MM(a0f, b0f);
        if (i < 11) { LDA(a0f, ks + 2); LDB(b0f, ks + 2); }
        MM(a1f, b1f);
    }
#undef LDA
#undef LDB
#undef MM

    float bv[2];
    bv[0] = pb[c0w + cl];
    bv[1] = pb[c0w + 16 + cl];

    // C/D layout: col=lane&15, row=(lane>>4)*4+r  [proven R1-R19]
    #pragma unroll
    for (int mt = 0; mt < 2; ++mt)
        #pragma unroll
        for (int nt = 0; nt < 2; ++nt)
            #pragma unroll
            for (int r = 0; r < 4; ++r)
                out[((size_t)b * NW + w0 + mt * 16 + kg * 4 + r) * ND + c0w + nt * 16 + cl]
                    = acc[mt][nt][r] + bv[nt];
}

extern "C" void kernel_launch(void* const* d_in, const int* in_sizes, int n_in,
                              void* d_out, int out_size, void* d_ws, size_t ws_size,
                              hipStream_t stream) {
    const float* hs  = (const float*)d_in[0];
    const int*   wid = (const int*)d_in[1];
    const float* pw  = (const float*)d_in[2];
    const float* pb  = (const float*)d_in[3];
    float* out = (float*)d_out;

    unsigned short* wt2 = (unsigned short*)d_ws;     // 393216 B

    prep_wt2<<<192, 256, 0, stream>>>(pw, wt2);
    fused<<<NB * (NW / 32), 512, 0, stream>>>(hs, wid, wt2, pb, out);
}